// Round 14
// baseline (1566.172 us; speedup 1.0000x reference)
//
#include <hip/hip_runtime.h>
#include <hip/hip_bf16.h>
#include <stdint.h>

#define B_ 4
#define L_ 4096
#define D_ 2048
#define TD_ (3 * D_)          // 6144
#define CHUNKS 128
#define CLEN (L_ / CHUNKS)    // 32
#define M_ (B_ * L_)          // 16384
#define K_ 2048
#define NT (K_ / 64)          // 32 K-tiles of BK=64

typedef __bf16 bf16x8 __attribute__((ext_vector_type(8)));
typedef float f32x4 __attribute__((ext_vector_type(4)));
typedef ushort u16x8 __attribute__((ext_vector_type(8)));

__device__ __forceinline__ ushort f2bf(float f) {
  uint32_t u = __builtin_bit_cast(uint32_t, f);
  u += 0x7fffu + ((u >> 16) & 1u);   // RTNE
  return (ushort)(u >> 16);
}

__device__ __forceinline__ float bf2f(ushort u) {
  return __builtin_bit_cast(float, (uint32_t)u << 16);
}

__device__ __forceinline__ float phi_f(float x) {
  return x > 0.f ? x + 1.f : __expf(x);   // elu(x)+1
}

__device__ __forceinline__ void gload_lds16(const ushort* g, ushort* l) {
  __builtin_amdgcn_global_load_lds(
      (__attribute__((address_space(1))) void*)(g),
      (__attribute__((address_space(3))) void*)(l), 16, 0, 0);
}

#define SBAR() __builtin_amdgcn_s_barrier()
#define SCHED0() __builtin_amdgcn_sched_barrier(0)
#define MFMA16(a, b, c) __builtin_amdgcn_mfma_f32_16x16x32_bf16((a), (b), (c), 0, 0, 0)

// ---------------- f32 -> bf16 conversion ----------------
__global__ void cvt_bf16_kernel(const float* __restrict__ in,
                                ushort* __restrict__ out, int n4) {
  int i = blockIdx.x * blockDim.x + threadIdx.x;
  if (i >= n4) return;
  float4 v = reinterpret_cast<const float4*>(in)[i];
  ushort4 o;
  o.x = f2bf(v.x); o.y = f2bf(v.y); o.z = f2bf(v.z); o.w = f2bf(v.w);
  reinterpret_cast<ushort4*>(out)[i] = o;
}

// ---------------- 256x256 4-wave GEMM core (128x128 per wave) ----------------
// LDS read traffic per K-tile drops 192->128 KB vs the 8-wave split (A and B
// each duplicated only x2 across waves). Schedule = r9's validated
// single-barrier-per-tile loop.
// Stage one 128-row x 64-col bf16 half-tile (16 KiB) with 256 threads
// (4 x 16B per thread); row-XOR swizzle on the GLOBAL source, LDS linear.
__device__ __forceinline__ void stage_half(const ushort* __restrict__ G,
                                           int row0, int k0, char* lds_half,
                                           int tid) {
#pragma unroll
  for (int lp = 0; lp < 4; ++lp) {
    const int p = lp * 4096 + tid * 16;        // byte offset in half-tile
    const int row = p >> 7;                    // 0..127
    const int cb = (p & 127) ^ ((row & 7) << 4);
    gload_lds16(G + (size_t)(row0 + row) * K_ + k0 + (cb >> 1),
                (ushort*)(lds_half + p));
  }
}

#define RD(p, off) (*reinterpret_cast<const bf16x8*>((p) + (off)))

// One K-tile (BK=64), ONE barrier + ONE vmcnt per tile (r9-validated
// hazard logic). c = buffer parity (literal 0/1). A-rows processed in two
// halves (lo: wm..wm+63, hi: wm+64..wm+127) reusing af regs to cap liveness.
#define KTILE(t, c)                                                            \
  {                                                                            \
    if ((t) + 1 < NT) {                                                        \
      const int kn = ((t) + 1) * 64;                                           \
      stage_half(A, rA, kn, lsA + (1 - (c)) * 32768, tid);                     \
      stage_half(A, rA + 128, kn, lsA + (1 - (c)) * 32768 + 16384, tid);       \
      stage_half(Bm, rB, kn, lsB + (1 - (c)) * 32768, tid);                    \
      stage_half(Bm, rB + 128, kn, lsB + (1 - (c)) * 32768 + 16384, tid);      \
    }                                                                          \
    SCHED0();                                                                  \
    _Pragma("unroll") for (int i = 0; i < 4; ++i) {                            \
      af[i][0] = RD(bA0, (c) * 32768 + i * 2048);                              \
      af[i][1] = RD(bA1, (c) * 32768 + i * 2048);                              \
    }                                                                          \
    _Pragma("unroll") for (int j = 0; j < 8; ++j) {                            \
      bfr[j][0] = RD(bB0, (c) * 32768 + j * 2048);                             \
      bfr[j][1] = RD(bB1, (c) * 32768 + j * 2048);                             \
    }                                                                          \
    __builtin_amdgcn_s_setprio(1);                                             \
    _Pragma("unroll") for (int ks = 0; ks < 2; ++ks)                           \
    _Pragma("unroll") for (int i = 0; i < 4; ++i)                              \
    _Pragma("unroll") for (int j = 0; j < 8; ++j)                              \
        acc[i][j] = MFMA16(af[i][ks], bfr[j][ks], acc[i][j]);                  \
    __builtin_amdgcn_s_setprio(0);                                             \
    _Pragma("unroll") for (int i = 0; i < 4; ++i) {                            \
      af[i][0] = RD(bA0, (c) * 32768 + 8192 + i * 2048);                       \
      af[i][1] = RD(bA1, (c) * 32768 + 8192 + i * 2048);                       \
    }                                                                          \
    __builtin_amdgcn_s_setprio(1);                                             \
    _Pragma("unroll") for (int ks = 0; ks < 2; ++ks)                           \
    _Pragma("unroll") for (int i = 0; i < 4; ++i)                              \
    _Pragma("unroll") for (int j = 0; j < 8; ++j)                              \
        acc[4 + i][j] = MFMA16(af[i][ks], bfr[j][ks], acc[4 + i][j]);          \
    __builtin_amdgcn_s_setprio(0);                                             \
    SCHED0();                                                                  \
    asm volatile("s_waitcnt vmcnt(0)" ::: "memory");                           \
    SBAR();                                                                    \
    SCHED0();                                                                  \
  }

__device__ __forceinline__ void gemm_core(const ushort* __restrict__ A,
                                          const ushort* __restrict__ Bm,
                                          int bm, int bn, char* ls,
                                          f32x4 (&acc)[8][8]) {
  const int tid = threadIdx.x;                  // 0..255
  const int lane = tid & 63, wid = tid >> 6;    // wid 0..3
  const int wm = (wid >> 1) * 128, wn = (wid & 1) * 128;
  const int l16 = lane & 15, kg = lane >> 4;
  const int rA = bm * 256, rB = bn * 256;

  char* lsA = ls;             // A tiles: buf0 @0, buf1 @32768 (32 KiB each)
  char* lsB = ls + 65536;     // B tiles: buf0 @0, buf1 @32768
  // Rows 0..255 are linear at row*128 within a 32 KiB tile (halves abut).

  const int v16 = (l16 & 7) << 4;
  const int c0 = (kg * 16) ^ v16;
  const int c1 = (64 + kg * 16) ^ v16;
  const char* bA0 = lsA + (wm + l16) * 128 + c0;
  const char* bA1 = lsA + (wm + l16) * 128 + c1;
  const char* bB0 = lsB + (wn + l16) * 128 + c0;
  const char* bB1 = lsB + (wn + l16) * 128 + c1;

  // Prologue: tile 0 -> buf0, drain, barrier.
  stage_half(A, rA, 0, lsA, tid);
  stage_half(A, rA + 128, 0, lsA + 16384, tid);
  stage_half(Bm, rB, 0, lsB, tid);
  stage_half(Bm, rB + 128, 0, lsB + 16384, tid);
  asm volatile("s_waitcnt vmcnt(0)" ::: "memory");
  SBAR();
  SCHED0();

  bf16x8 af[4][2], bfr[8][2];
#pragma unroll 1
  for (int t2 = 0; t2 < NT; t2 += 2) {
    KTILE(t2, 0);
    KTILE(t2 + 1, 1);
  }
}

// ---------------- GEMM1: qkv = x @ Wqkv^T, bf16 out split q/k/v ----------------
__global__ __launch_bounds__(256, 1) void gemm_qkv8(
    const ushort* __restrict__ A, const ushort* __restrict__ Bm,
    ushort* __restrict__ qb, ushort* __restrict__ kb, ushort* __restrict__ vb) {
  extern __shared__ char ls[];
  const int nwg = gridDim.x;                    // 1536, %8==0
  const int wg = blockIdx.x;
  const int swz = (wg & 7) * (nwg >> 3) + (wg >> 3);
  const int MT = M_ / 256;                      // 64
  const int bm = swz % MT, bn = swz / MT;       // bn in [0,24)

  f32x4 acc[8][8] = {};
  gemm_core(A, Bm, bm, bn, ls, acc);

  const int seg = bn >> 3;                      // 0=q 1=k 2=v (8 tiles each)
  ushort* dst = seg == 0 ? qb : (seg == 1 ? kb : vb);
  const int colbase = bn * 256 - seg * 2048;
  const int tid = threadIdx.x;
  const int lane = tid & 63, wid = tid >> 6;
  const int wm = (wid >> 1) * 128, wn = (wid & 1) * 128;
  const int l16 = lane & 15, kg = lane >> 4;
#pragma unroll
  for (int i = 0; i < 8; ++i) {
    const int row0 = bm * 256 + wm + i * 16 + kg * 4;
#pragma unroll
    for (int j = 0; j < 8; ++j) {
      const int col = colbase + wn + j * 16 + l16;
      ushort* cp = dst + (size_t)row0 * D_ + col;
#pragma unroll
      for (int r = 0; r < 4; ++r) cp[(size_t)r * D_] = f2bf(acc[i][j][r]);
    }
  }
}

// ---------------- GEMM2: out = (attn @ Wout^T) * scale, f32 out ----------------
__global__ __launch_bounds__(256, 1) void gemm_out8(
    const ushort* __restrict__ A, const ushort* __restrict__ Bm,
    float* __restrict__ C, float scale) {
  extern __shared__ char ls[];
  const int nwg = gridDim.x;                    // 512, %8==0
  const int wg = blockIdx.x;
  const int swz = (wg & 7) * (nwg >> 3) + (wg >> 3);
  const int MT = M_ / 256;
  const int bm = swz % MT, bn = swz / MT;       // bn in [0,8)

  f32x4 acc[8][8] = {};
  gemm_core(A, Bm, bm, bn, ls, acc);

  const int tid = threadIdx.x;
  const int lane = tid & 63, wid = tid >> 6;
  const int wm = (wid >> 1) * 128, wn = (wid & 1) * 128;
  const int l16 = lane & 15, kg = lane >> 4;
#pragma unroll
  for (int i = 0; i < 8; ++i) {
    const int row0 = bm * 256 + wm + i * 16 + kg * 4;
#pragma unroll
    for (int j = 0; j < 8; ++j) {
      const int col = bn * 256 + wn + j * 16 + l16;
      float* cp = C + (size_t)row0 * D_ + col;
#pragma unroll
      for (int r = 0; r < 4; ++r) cp[(size_t)r * D_] = acc[i][j][r] * scale;
    }
  }
}

// ---------------- scan pass A: per-chunk sums of phi(k) and phi(k)*v ----------------
__global__ void chunk_sums_kernel(const ushort* __restrict__ kb,
                                  const ushort* __restrict__ vb,
                                  float* __restrict__ sums) {
  const int d0 = threadIdx.x * 8;
  const int b = blockIdx.y, c = blockIdx.z;
  float sk[8] = {}, skv[8] = {};
  const size_t rowbase = (size_t)b * L_ + (size_t)c * CLEN;
  for (int l = 0; l < CLEN; ++l) {
    const size_t idx = (rowbase + l) * D_ + d0;
    u16x8 k8 = *reinterpret_cast<const u16x8*>(kb + idx);
    u16x8 v8 = *reinterpret_cast<const u16x8*>(vb + idx);
#pragma unroll
    for (int j = 0; j < 8; ++j) {
      float k = phi_f(bf2f(k8[j]));
      sk[j] += k;
      skv[j] = fmaf(k, bf2f(v8[j]), skv[j]);
    }
  }
  float* s = sums + ((size_t)(b * CHUNKS + c) * 2) * D_ + d0;
#pragma unroll
  for (int j = 0; j < 8; ++j) {
    s[j] = sk[j];
    s[D_ + j] = skv[j];
  }
}

// ---------------- scan pass B: exclusive prefix over chunks ----------------
__global__ void chunk_prefix_kernel(float* __restrict__ sums) {
  const int idx = blockIdx.x * 256 + threadIdx.x;  // b*D + d
  const int b = idx >> 11, d = idx & (D_ - 1);
  float rk = 0.f, rkv = 0.f;
  for (int c = 0; c < CHUNKS; ++c) {
    float* s = sums + ((size_t)(b * CHUNKS + c) * 2) * D_ + d;
    float sk = s[0], skv = s[D_];
    s[0] = rk;
    s[D_] = rkv;
    rk += sk;
    rkv += skv;
  }
}

// ---------------- scan pass C: cumsum + out = q*kv/(q*k+eps) ----------------
__global__ void apply_kernel(const ushort* __restrict__ qb,
                             const ushort* __restrict__ kb,
                             const ushort* __restrict__ vb,
                             const float* __restrict__ sums,
                             ushort* __restrict__ outb) {
  const int d0 = threadIdx.x * 8;
  const int b = blockIdx.y, c = blockIdx.z;
  const float* s = sums + ((size_t)(b * CHUNKS + c) * 2) * D_ + d0;
  float rk[8], rkv[8];
#pragma unroll
  for (int j = 0; j < 8; ++j) {
    rk[j] = s[j];
    rkv[j] = s[D_ + j];
  }
  const size_t rowbase = (size_t)b * L_ + (size_t)c * CLEN;
  for (int l = 0; l < CLEN; ++l) {
    const size_t idx = (rowbase + l) * D_ + d0;
    u16x8 q8 = *reinterpret_cast<const u16x8*>(qb + idx);
    u16x8 k8 = *reinterpret_cast<const u16x8*>(kb + idx);
    u16x8 v8 = *reinterpret_cast<const u16x8*>(vb + idx);
    u16x8 o8;
#pragma unroll
    for (int j = 0; j < 8; ++j) {
      float q = phi_f(bf2f(q8[j]));
      float k = phi_f(bf2f(k8[j]));
      float v = bf2f(v8[j]);
      rkv[j] = fmaf(k, v, rkv[j]);
      rk[j] += k;
      float o = (q * rkv[j]) / fmaf(q, rk[j], 1e-9f);
      o8[j] = f2bf(o);
    }
    *reinterpret_cast<u16x8*>(outb + idx) = o8;
  }
}

extern "C" void kernel_launch(void* const* d_in, const int* in_sizes, int n_in,
                              void* d_out, int out_size, void* d_ws, size_t ws_size,
                              hipStream_t stream) {
  (void)in_sizes; (void)n_in; (void)out_size; (void)ws_size;
  const float* x = (const float*)d_in[0];
  const float* Wqkv = (const float*)d_in[1];
  const float* Wout = (const float*)d_in[2];
  float* out = (float*)d_out;

  // k,v (bf16) live inside d_out; dead before GEMM2 overwrites d_out.
  ushort* kb = (ushort*)d_out;
  ushort* vb = kb + (size_t)M_ * D_;

  char* ws = (char*)d_ws;
  size_t off = 0;
  auto alloc = [&](size_t bytes) -> void* {
    off = (off + 255) & ~(size_t)255;
    void* p = ws + off;
    off += bytes;
    return p;
  };
  ushort* qb = (ushort*)alloc((size_t)M_ * D_ * 2);               // 64 MB
  ushort* xb = (ushort*)alloc((size_t)M_ * D_ * 2);               // 64 MB
  ushort* wqb = (ushort*)alloc((size_t)TD_ * D_ * 2);             // 24 MB
  ushort* wob = (ushort*)alloc((size_t)D_ * D_ * 2);              // 8 MB
  float* sums = (float*)alloc((size_t)B_ * CHUNKS * 2 * D_ * 4);  // 8 MB
  ushort* outb = xb;  // alias: xb dead after GEMM1

  (void)hipFuncSetAttribute((const void*)gemm_qkv8,
                            hipFuncAttributeMaxDynamicSharedMemorySize, 131072);
  (void)hipFuncSetAttribute((const void*)gemm_out8,
                            hipFuncAttributeMaxDynamicSharedMemorySize, 131072);

  cvt_bf16_kernel<<<(M_ * D_ / 4 + 255) / 256, 256, 0, stream>>>(x, xb, M_ * D_ / 4);
  cvt_bf16_kernel<<<(TD_ * D_ / 4 + 255) / 256, 256, 0, stream>>>(Wqkv, wqb, TD_ * D_ / 4);
  cvt_bf16_kernel<<<(D_ * D_ / 4 + 255) / 256, 256, 0, stream>>>(Wout, wob, D_ * D_ / 4);

  gemm_qkv8<<<dim3((TD_ / 256) * (M_ / 256)), 256, 131072, stream>>>(xb, wqb, qb, kb, vb);

  chunk_sums_kernel<<<dim3(1, B_, CHUNKS), 256, 0, stream>>>(kb, vb, sums);
  chunk_prefix_kernel<<<dim3(B_ * D_ / 256), 256, 0, stream>>>(sums);
  apply_kernel<<<dim3(1, B_, CHUNKS), 256, 0, stream>>>(qb, kb, vb, sums, outb);

  gemm_out8<<<dim3((D_ / 256) * (M_ / 256)), 256, 131072, stream>>>(outb, wob, out,
                                                                    0.08838834764831845f);
}

// Round 15
// 621.338 us; speedup vs baseline: 2.5206x; 2.5206x over previous
//
#include <hip/hip_runtime.h>
#include <hip/hip_bf16.h>
#include <stdint.h>

#define B_ 4
#define L_ 4096
#define D_ 2048
#define TD_ (3 * D_)          // 6144
#define CHUNKS 128
#define CLEN (L_ / CHUNKS)    // 32
#define M_ (B_ * L_)          // 16384
#define K_ 2048
#define NT (K_ / 64)          // 32 K-tiles of BK=64

typedef __bf16 bf16x8 __attribute__((ext_vector_type(8)));
typedef float f32x4 __attribute__((ext_vector_type(4)));
typedef ushort u16x8 __attribute__((ext_vector_type(8)));

__device__ __forceinline__ ushort f2bf(float f) {
  uint32_t u = __builtin_bit_cast(uint32_t, f);
  u += 0x7fffu + ((u >> 16) & 1u);   // RTNE
  return (ushort)(u >> 16);
}

__device__ __forceinline__ float bf2f(ushort u) {
  return __builtin_bit_cast(float, (uint32_t)u << 16);
}

__device__ __forceinline__ float phi_f(float x) {
  return x > 0.f ? x + 1.f : __expf(x);   // elu(x)+1
}

__device__ __forceinline__ void gload_lds16(const ushort* g, ushort* l) {
  __builtin_amdgcn_global_load_lds(
      (__attribute__((address_space(1))) void*)(g),
      (__attribute__((address_space(3))) void*)(l), 16, 0, 0);
}

#define SBAR() __builtin_amdgcn_s_barrier()
#define SCHED0() __builtin_amdgcn_sched_barrier(0)
#define MFMA16(a, b, c) __builtin_amdgcn_mfma_f32_16x16x32_bf16((a), (b), (c), 0, 0, 0)

// ---------------- f32 -> bf16 conversion ----------------
__global__ void cvt_bf16_kernel(const float* __restrict__ in,
                                ushort* __restrict__ out, int n4) {
  int i = blockIdx.x * blockDim.x + threadIdx.x;
  if (i >= n4) return;
  float4 v = reinterpret_cast<const float4*>(in)[i];
  ushort4 o;
  o.x = f2bf(v.x); o.y = f2bf(v.y); o.z = f2bf(v.z); o.w = f2bf(v.w);
  reinterpret_cast<ushort4*>(out)[i] = o;
}

// ---------------- 256x256 GEMM core: 1 barrier + COUNTED vmcnt per tile ---
// A double-buffered (2x32 KB), B TRIPLE-buffered (3x32 KB) -> 160 KB LDS
// (full CU pool; gfx950 allows 160 KB/workgroup — AITER fmha does this).
// The third B buffer is what lets the end-of-tile wait be vmcnt(4) instead
// of a full vmcnt(0) drain while keeping r9's single barrier.
__device__ __forceinline__ void stage_half(const ushort* __restrict__ G,
                                           int row0, int k0, char* lds_half,
                                           int tid) {
#pragma unroll
  for (int lp = 0; lp < 2; ++lp) {
    const int p = lp * 8192 + tid * 16;        // byte offset in half-tile
    const int row = p >> 7;                    // 0..127
    const int cb = (p & 127) ^ ((row & 7) << 4);
    gload_lds16(G + (size_t)(row0 + row) * K_ + k0 + (cb >> 1),
                (ushort*)(lds_half + p));
  }
}

#define RD(p, off) (*reinterpret_cast<const bf16x8*>((p) + (off)))

// Per-tile schedule (per-thread vmem accounting, 4 loads per tile-operand):
//   entering tile t: outstanding = B(t+1) [<=4]; A(t),B(t) landed.
//   issue A(t+1)->bufA[1-ca] (4), B(t+2)->bufB[cb+2 mod 3] (4)  -> <=12
//   ds_read af-lo/bfr -> 32 MFMA -> af-hi -> 32 MFMA
//   vmcnt(4): retires 8 oldest = B(t+1), A(t+1); leaves B(t+2). SBAR.
// LDS hazards: every staged-over buffer's readers completed before the
// PREVIOUS tile's barrier (ds_reads complete before their MFMAs). Tail
// (t+2>=NT): vmcnt(0).
__device__ __forceinline__ void gemm_core(const ushort* __restrict__ A,
                                          const ushort* __restrict__ Bm,
                                          int bm, int bn, char* ls,
                                          f32x4 (&acc)[8][4]) {
  const int tid = threadIdx.x;
  const int lane = tid & 63, wid = tid >> 6;
  const int wm = (wid >> 2) * 128, wn = (wid & 3) * 64;
  const int l16 = lane & 15, kg = lane >> 4;
  const int rA = bm * 256, rB = bn * 256;

  char* lsA = ls;             // A tiles: buf0 @0, buf1 @32768
  char* lsB = ls + 65536;     // B tiles: buf0 @0, buf1 @32768, buf2 @65536

  const int v16 = (l16 & 7) << 4;
  const int c0 = (kg * 16) ^ v16;
  const int c1 = (64 + kg * 16) ^ v16;
  const char* bA0 = lsA + (wm + l16) * 128 + c0;
  const char* bA1 = lsA + (wm + l16) * 128 + c1;
  const char* bB0 = lsB + (wn + l16) * 128 + c0;
  const char* bB1 = lsB + (wn + l16) * 128 + c1;

  // Prologue: A(0)->a0 (4), B(0)->b0 (4), B(1)->b1 (4); vmcnt(4) ->
  // A(0),B(0) landed, B(1) <=4 in flight (steady-state invariant).
  stage_half(A, rA, 0, lsA, tid);
  stage_half(A, rA + 128, 0, lsA + 16384, tid);
  stage_half(Bm, rB, 0, lsB, tid);
  stage_half(Bm, rB + 128, 0, lsB + 16384, tid);
  stage_half(Bm, rB, 64, lsB + 32768, tid);
  stage_half(Bm, rB + 128, 64, lsB + 32768 + 16384, tid);
  asm volatile("s_waitcnt vmcnt(4)" ::: "memory");
  SBAR();
  SCHED0();

  bf16x8 af[4][2], bfr[4][2];
  int caOff = 0;    // A parity byte offset: 0 / 32768
  int cbOff = 0;    // B ring byte offset: 0 / 32768 / 65536

#pragma unroll 1
  for (int t = 0; t < NT; ++t) {
    const int caN = caOff ^ 32768;
    int cb2 = cbOff + 65536;
    if (cb2 >= 98304) cb2 -= 98304;           // (cb+2) mod 3, in bytes

    if (t + 1 < NT) {
      const int kn = (t + 1) * 64;
      stage_half(A, rA, kn, lsA + caN, tid);
      stage_half(A, rA + 128, kn, lsA + caN + 16384, tid);
    }
    if (t + 2 < NT) {
      const int kn2 = (t + 2) * 64;
      stage_half(Bm, rB, kn2, lsB + cb2, tid);
      stage_half(Bm, rB + 128, kn2, lsB + cb2 + 16384, tid);
    }
    SCHED0();

#pragma unroll
    for (int i = 0; i < 4; ++i) {
      af[i][0] = RD(bA0, caOff + i * 2048);
      af[i][1] = RD(bA1, caOff + i * 2048);
    }
#pragma unroll
    for (int j = 0; j < 4; ++j) {
      bfr[j][0] = RD(bB0, cbOff + j * 2048);
      bfr[j][1] = RD(bB1, cbOff + j * 2048);
    }
    __builtin_amdgcn_s_setprio(1);
#pragma unroll
    for (int i = 0; i < 4; ++i)
#pragma unroll
      for (int j = 0; j < 4; ++j)
#pragma unroll
        for (int ks = 0; ks < 2; ++ks)
          acc[i][j] = MFMA16(af[i][ks], bfr[j][ks], acc[i][j]);
    __builtin_amdgcn_s_setprio(0);

#pragma unroll
    for (int i = 0; i < 4; ++i) {
      af[i][0] = RD(bA0, caOff + 8192 + i * 2048);
      af[i][1] = RD(bA1, caOff + 8192 + i * 2048);
    }
    __builtin_amdgcn_s_setprio(1);
#pragma unroll
    for (int i = 0; i < 4; ++i)
#pragma unroll
      for (int j = 0; j < 4; ++j)
#pragma unroll
        for (int ks = 0; ks < 2; ++ks)
          acc[4 + i][j] = MFMA16(af[i][ks], bfr[j][ks], acc[4 + i][j]);
    __builtin_amdgcn_s_setprio(0);

    SCHED0();
    if (t + 2 < NT) {
      asm volatile("s_waitcnt vmcnt(4)" ::: "memory");
    } else {
      asm volatile("s_waitcnt vmcnt(0)" ::: "memory");
    }
    SBAR();
    SCHED0();

    caOff = caN;
    cbOff += 32768;
    if (cbOff >= 98304) cbOff -= 98304;
  }
}

// ---------------- GEMM1: qkv = x @ Wqkv^T, bf16 out split q/k/v ----------------
__global__ __launch_bounds__(512, 2) void gemm_qkv8(
    const ushort* __restrict__ A, const ushort* __restrict__ Bm,
    ushort* __restrict__ qb, ushort* __restrict__ kb, ushort* __restrict__ vb) {
  extern __shared__ char ls[];
  const int nwg = gridDim.x;                    // 1536, %8==0
  const int wg = blockIdx.x;
  const int swz = (wg & 7) * (nwg >> 3) + (wg >> 3);
  const int MT = M_ / 256;                      // 64
  const int bm = swz % MT, bn = swz / MT;       // bn in [0,24)

  f32x4 acc[8][4] = {};
  gemm_core(A, Bm, bm, bn, ls, acc);

  const int seg = bn >> 3;                      // 0=q 1=k 2=v (8 tiles each)
  ushort* dst = seg == 0 ? qb : (seg == 1 ? kb : vb);
  const int colbase = bn * 256 - seg * 2048;
  const int tid = threadIdx.x;
  const int lane = tid & 63, wid = tid >> 6;
  const int wm = (wid >> 2) * 128, wn = (wid & 3) * 64;
  const int l16 = lane & 15, kg = lane >> 4;
#pragma unroll
  for (int i = 0; i < 8; ++i) {
    const int row0 = bm * 256 + wm + i * 16 + kg * 4;
#pragma unroll
    for (int j = 0; j < 4; ++j) {
      const int col = colbase + wn + j * 16 + l16;
      ushort* cp = dst + (size_t)row0 * D_ + col;
#pragma unroll
      for (int r = 0; r < 4; ++r) cp[(size_t)r * D_] = f2bf(acc[i][j][r]);
    }
  }
}

// ---------------- GEMM2: out = (attn @ Wout^T) * scale, f32 out ----------------
__global__ __launch_bounds__(512, 2) void gemm_out8(
    const ushort* __restrict__ A, const ushort* __restrict__ Bm,
    float* __restrict__ C, float scale) {
  extern __shared__ char ls[];
  const int nwg = gridDim.x;                    // 512, %8==0
  const int wg = blockIdx.x;
  const int swz = (wg & 7) * (nwg >> 3) + (wg >> 3);
  const int MT = M_ / 256;
  const int bm = swz % MT, bn = swz / MT;       // bn in [0,8)

  f32x4 acc[8][4] = {};
  gemm_core(A, Bm, bm, bn, ls, acc);

  const int tid = threadIdx.x;
  const int lane = tid & 63, wid = tid >> 6;
  const int wm = (wid >> 2) * 128, wn = (wid & 3) * 64;
  const int l16 = lane & 15, kg = lane >> 4;
#pragma unroll
  for (int i = 0; i < 8; ++i) {
    const int row0 = bm * 256 + wm + i * 16 + kg * 4;
#pragma unroll
    for (int j = 0; j < 4; ++j) {
      const int col = bn * 256 + wn + j * 16 + l16;
      float* cp = C + (size_t)row0 * D_ + col;
#pragma unroll
      for (int r = 0; r < 4; ++r) cp[(size_t)r * D_] = acc[i][j][r] * scale;
    }
  }
}

// ---------------- scan pass A: per-chunk sums of phi(k) and phi(k)*v ----------------
__global__ void chunk_sums_kernel(const ushort* __restrict__ kb,
                                  const ushort* __restrict__ vb,
                                  float* __restrict__ sums) {
  const int d0 = threadIdx.x * 8;
  const int b = blockIdx.y, c = blockIdx.z;
  float sk[8] = {}, skv[8] = {};
  const size_t rowbase = (size_t)b * L_ + (size_t)c * CLEN;
  for (int l = 0; l < CLEN; ++l) {
    const size_t idx = (rowbase + l) * D_ + d0;
    u16x8 k8 = *reinterpret_cast<const u16x8*>(kb + idx);
    u16x8 v8 = *reinterpret_cast<const u16x8*>(vb + idx);
#pragma unroll
    for (int j = 0; j < 8; ++j) {
      float k = phi_f(bf2f(k8[j]));
      sk[j] += k;
      skv[j] = fmaf(k, bf2f(v8[j]), skv[j]);
    }
  }
  float* s = sums + ((size_t)(b * CHUNKS + c) * 2) * D_ + d0;
#pragma unroll
  for (int j = 0; j < 8; ++j) {
    s[j] = sk[j];
    s[D_ + j] = skv[j];
  }
}

// ---------------- scan pass B: exclusive prefix over chunks ----------------
__global__ void chunk_prefix_kernel(float* __restrict__ sums) {
  const int idx = blockIdx.x * 256 + threadIdx.x;  // b*D + d
  const int b = idx >> 11, d = idx & (D_ - 1);
  float rk = 0.f, rkv = 0.f;
  for (int c = 0; c < CHUNKS; ++c) {
    float* s = sums + ((size_t)(b * CHUNKS + c) * 2) * D_ + d;
    float sk = s[0], skv = s[D_];
    s[0] = rk;
    s[D_] = rkv;
    rk += sk;
    rkv += skv;
  }
}

// ---------------- scan pass C: cumsum + out = q*kv/(q*k+eps) ----------------
__global__ void apply_kernel(const ushort* __restrict__ qb,
                             const ushort* __restrict__ kb,
                             const ushort* __restrict__ vb,
                             const float* __restrict__ sums,
                             ushort* __restrict__ outb) {
  const int d0 = threadIdx.x * 8;
  const int b = blockIdx.y, c = blockIdx.z;
  const float* s = sums + ((size_t)(b * CHUNKS + c) * 2) * D_ + d0;
  float rk[8], rkv[8];
#pragma unroll
  for (int j = 0; j < 8; ++j) {
    rk[j] = s[j];
    rkv[j] = s[D_ + j];
  }
  const size_t rowbase = (size_t)b * L_ + (size_t)c * CLEN;
  for (int l = 0; l < CLEN; ++l) {
    const size_t idx = (rowbase + l) * D_ + d0;
    u16x8 q8 = *reinterpret_cast<const u16x8*>(qb + idx);
    u16x8 k8 = *reinterpret_cast<const u16x8*>(kb + idx);
    u16x8 v8 = *reinterpret_cast<const u16x8*>(vb + idx);
    u16x8 o8;
#pragma unroll
    for (int j = 0; j < 8; ++j) {
      float q = phi_f(bf2f(q8[j]));
      float k = phi_f(bf2f(k8[j]));
      float v = bf2f(v8[j]);
      rkv[j] = fmaf(k, v, rkv[j]);
      rk[j] += k;
      float o = (q * rkv[j]) / fmaf(q, rk[j], 1e-9f);
      o8[j] = f2bf(o);
    }
    *reinterpret_cast<u16x8*>(outb + idx) = o8;
  }
}

extern "C" void kernel_launch(void* const* d_in, const int* in_sizes, int n_in,
                              void* d_out, int out_size, void* d_ws, size_t ws_size,
                              hipStream_t stream) {
  (void)in_sizes; (void)n_in; (void)out_size; (void)ws_size;
  const float* x = (const float*)d_in[0];
  const float* Wqkv = (const float*)d_in[1];
  const float* Wout = (const float*)d_in[2];
  float* out = (float*)d_out;

  // k,v (bf16) live inside d_out; dead before GEMM2 overwrites d_out.
  ushort* kb = (ushort*)d_out;
  ushort* vb = kb + (size_t)M_ * D_;

  char* ws = (char*)d_ws;
  size_t off = 0;
  auto alloc = [&](size_t bytes) -> void* {
    off = (off + 255) & ~(size_t)255;
    void* p = ws + off;
    off += bytes;
    return p;
  };
  ushort* qb = (ushort*)alloc((size_t)M_ * D_ * 2);               // 64 MB
  ushort* xb = (ushort*)alloc((size_t)M_ * D_ * 2);               // 64 MB
  ushort* wqb = (ushort*)alloc((size_t)TD_ * D_ * 2);             // 24 MB
  ushort* wob = (ushort*)alloc((size_t)D_ * D_ * 2);              // 8 MB
  float* sums = (float*)alloc((size_t)B_ * CHUNKS * 2 * D_ * 4);  // 8 MB
  ushort* outb = xb;  // alias: xb dead after GEMM1

  (void)hipFuncSetAttribute((const void*)gemm_qkv8,
                            hipFuncAttributeMaxDynamicSharedMemorySize, 163840);
  (void)hipFuncSetAttribute((const void*)gemm_out8,
                            hipFuncAttributeMaxDynamicSharedMemorySize, 163840);

  cvt_bf16_kernel<<<(M_ * D_ / 4 + 255) / 256, 256, 0, stream>>>(x, xb, M_ * D_ / 4);
  cvt_bf16_kernel<<<(TD_ * D_ / 4 + 255) / 256, 256, 0, stream>>>(Wqkv, wqb, TD_ * D_ / 4);
  cvt_bf16_kernel<<<(D_ * D_ / 4 + 255) / 256, 256, 0, stream>>>(Wout, wob, D_ * D_ / 4);

  gemm_qkv8<<<dim3((TD_ / 256) * (M_ / 256)), 512, 163840, stream>>>(xb, wqb, qb, kb, vb);

  chunk_sums_kernel<<<dim3(1, B_, CHUNKS), 256, 0, stream>>>(kb, vb, sums);
  chunk_prefix_kernel<<<dim3(B_ * D_ / 256), 256, 0, stream>>>(sums);
  apply_kernel<<<dim3(1, B_, CHUNKS), 256, 0, stream>>>(qb, kb, vb, sums, outb);

  gemm_out8<<<dim3((D_ / 256) * (M_ / 256)), 512, 163840, stream>>>(outb, wob, out,
                                                                    0.08838834764831845f);
}